// Round 1
// baseline (85.096 us; speedup 1.0000x reference)
//
#include <hip/hip_runtime.h>
#include <hip/hip_fp16.h>

// 2D parallel-beam forward projection (Radon), ray-driven bilinear, matches jax ref.
// Strategy: per-block LDS staging of one 64-row image quarter as fp16 ROW-PAIRS:
//   Q[r][xl] = half2( v[qbase+r-1][x], v[qbase+r][x] ),  xl = x+2
// so one bilinear sample = 2 adjacent b32 LDS reads (ds_read2_b32) + lerp.
// Guard rows/cols are zero -> no per-tap masks needed.
// Work units (angle, det-chunk, t-quarter) distributed by work-stealing.

#define NVOL  256
#define NANG  180
#define NDET  363

constexpr int   ROWS      = 67;          // local pair rows 0..66 (0,65,66 guards/partial)
constexpr int   W         = 269;         // half2 words per row; real cols 2..257
constexpr int   LDS_WORDS = ROWS * W;    // 18023
constexpr size_t LDS_BYTES = (size_t)LDS_WORDS * 4;  // 72092 B -> 2 blocks/CU possible

__global__ __launch_bounds__(1024, 8)
void proj_kernel(const float* __restrict__ img, float* __restrict__ out,
                 unsigned int* __restrict__ cnt) {
    extern __shared__ unsigned int L[];
    const int tid    = threadIdx.x;
    const int bid    = blockIdx.x;
    const int batch  = bid & 1;
    const int quarter = (bid >> 1) & 3;
    const int qbase  = quarter << 6;

    // --- zero whole LDS (guards + pads) ---
    for (int i = tid; i < LDS_WORDS; i += 1024) L[i] = 0u;
    __syncthreads();

    // --- stage quarter as row-pairs ---
    const float4* img4 = (const float4*)(img + batch * NVOL * NVOL);
    for (int i = tid; i < 65 * 64; i += 1024) {
        int r = i >> 6, q = i & 63;                 // r: 0..64, q: float4 within row
        float4 lo = make_float4(0.f, 0.f, 0.f, 0.f);
        float4 hi = lo;
        if (r >= 1)  lo = img4[((qbase + r - 1) << 6) + q];   // row qbase+r-1 (ours iff r>=1)
        if (r <= 63) hi = img4[((qbase + r)     << 6) + q];   // row qbase+r   (ours iff r<=63)
        int base = r * W + 2 + (q << 2);            // half2 word index
        __half2* dst = (__half2*)&L[base];
        dst[0] = __floats2half2_rn(lo.x, hi.x);
        dst[1] = __floats2half2_rn(lo.y, hi.y);
        dst[2] = __floats2half2_rn(lo.z, hi.z);
        dst[3] = __floats2half2_rn(lo.w, hi.w);
    }
    __syncthreads();

    const __half2* Lh  = (const __half2*)L;
    const int lane     = tid & 63;
    unsigned int* ctr  = &cnt[(bid & 7) << 5];      // 128B-padded counter per (batch,quarter)
    const float  Bx    = 128.499f;
    const float  ylo   = (float)qbase - 128.499f;   // py bounds for this quarter
    const float  yhi   = (float)qbase - 63.501f;
    float* outb        = out + batch * (NANG * NDET);
    const unsigned NUNITS = NANG * 24;              // (angle, chunk(6), t-quarter(4))

    for (;;) {
        unsigned u = 0;
        if (lane == 0) u = atomicAdd(ctr, 1u);
        u = (unsigned)__shfl((int)u, 0);
        if (u >= NUNITS) break;

        int a   = (int)(u / 24u);
        int rem = (int)(u - 24u * (unsigned)(u / 24u));
        int ci  = rem >> 2;
        int tqi = rem & 3;
        int chunk = (0x2885A >> (ci * 3)) & 7;      // order {2,3,1,4,0,5}: long units first
        int tq    = (0xC9 >> (tqi * 2)) & 3;        // order {1,2,0,3}
        int klo = tq * 91;
        int khi = min(362, klo + 90);
        int det = (chunk << 6) + lane;

        float ang = (float)a * 0.017453292519943295f;
        float si, c;
        sincosf(ang, &si, &c);
        float s  = (float)det - 181.0f;
        float sx = s * c, sy = s * si;

        // slab-clip t so that px in [-Bx,Bx], py in [ylo,yhi]
        float tlo = -181.0f, thi = 181.0f;
        bool ok = det < NDET;
        if (si > 1e-6f) {
            tlo = fmaxf(tlo, (sx - Bx) / si);
            thi = fminf(thi, (sx + Bx) / si);
        } else if (fabsf(sx) > Bx) ok = false;
        if (c > 1e-6f) {
            tlo = fmaxf(tlo, (ylo - sy) / c);
            thi = fminf(thi, (yhi - sy) / c);
        } else if (c < -1e-6f) {
            tlo = fmaxf(tlo, (yhi - sy) / c);
            thi = fminf(thi, (ylo - sy) / c);
        } else if (sy < ylo || sy > yhi) ok = false;
        tlo += 1e-3f; thi -= 1e-3f;                 // drop only weight<=1e-3 edge taps

        int k0 = max(klo, max(0,   (int)ceilf(tlo + 181.0f)));
        int k1 = min(khi, min(362, (int)floorf(thi + 181.0f)));

        float acc = 0.0f;
        if (ok && k0 <= k1) {
            float fxc = sx + 129.5f;                // local x offset (+2 cols)
            float fyc = sy + 128.5f - (float)qbase; // local pair-row offset (+1 row)
            float t = (float)k0 - 181.0f;
            #pragma unroll 2
            for (int k = k0; k <= k1; ++k, t += 1.0f) {
                float fx = fmaf(t, -si, fxc);
                float fy = fmaf(t,  c,  fyc);
                float xf = floorf(fx), yf = floorf(fy);
                float wx = fx - xf,   wy = fy - yf;
                int ix = (int)xf, iy = (int)yf;
                int wb = iy * W + ix;
                __half2 h0 = Lh[wb];                // (v[iy_g][ix_g],   v[iy_g+1][ix_g])
                __half2 h1 = Lh[wb + 1];            // (v[iy_g][ix_g+1], v[iy_g+1][ix_g+1])
                float v00 = __low2float(h0), v10 = __high2float(h0);
                float v01 = __low2float(h1), v11 = __high2float(h1);
                float c0 = fmaf(wy, v10 - v00, v00);
                float c1 = fmaf(wy, v11 - v01, v01);
                acc += fmaf(wx, c1 - c0, c0);
            }
        }
        if (ok && acc != 0.0f) atomicAdd(&outb[a * NDET + det], acc);
    }
}

extern "C" void kernel_launch(void* const* d_in, const int* in_sizes, int n_in,
                              void* d_out, int out_size, void* d_ws, size_t ws_size,
                              hipStream_t stream) {
    const float* img = (const float*)d_in[0];
    float* out = (float*)d_out;
    unsigned int* cnt = (unsigned int*)d_ws;

    hipFuncSetAttribute((const void*)proj_kernel,
                        hipFuncAttributeMaxDynamicSharedMemorySize, (int)LDS_BYTES);
    hipMemsetAsync(d_out, 0, (size_t)out_size * sizeof(float), stream);
    hipMemsetAsync(d_ws, 0, 8 * 32 * sizeof(unsigned int), stream);
    proj_kernel<<<256, 1024, LDS_BYTES, stream>>>(img, out, cnt);
}

// Round 2
// 73.311 us; speedup vs baseline: 1.1608x; 1.1608x over previous
//
#include <hip/hip_runtime.h>
#include <hip/hip_fp16.h>

// 2D parallel-beam forward projection (Radon), ray-driven bilinear.
// Full image staged in LDS as fp16 (guard rows/cols = 0), one wave per ray,
// lanes t-major -> uniform loop bounds, shuffle-reduce, direct store (no atomics).
//
// LDS layout: halves H[ly][lx], ly = y+1 (0..258), lx = x+2 (0..261),
// row stride RW=131 dwords (odd -> good bank spread). Bilinear tap:
//   2x ds_read2_b32 (word w,w+1 of rows iy,iy+1) + v_alignbit parity select.

#define NVOL 256
#define NANG 180
#define NDET 363

constexpr int RW        = 131;                 // dwords per row
constexpr int NROWS     = 259;
constexpr int LDS_WORDS = NROWS * RW;          // 33929
constexpr size_t LDS_BYTES = (size_t)LDS_WORDS * 4;  // 135716 B -> 1 block/CU

constexpr int RCHUNK = 8;                                  // dets per work unit
constexpr int NCHUNK = (NDET + RCHUNK - 1) / RCHUNK;       // 46
constexpr int NU     = NANG * NCHUNK;                      // 8280 units per batch

__global__ __launch_bounds__(1024, 4)
void proj_kernel(const float* __restrict__ img, float* __restrict__ out,
                 unsigned int* __restrict__ cnt) {
    extern __shared__ unsigned int L[];
    const int tid   = threadIdx.x;
    const int bid   = blockIdx.x;
    const int batch = bid & 1;
    const int half  = (bid >> 1) & 1;          // unit-space half this block serves

    // --- zero LDS (covers guards + pads) ---
    for (int i = tid; i < LDS_WORDS; i += 1024) L[i] = 0u;
    __syncthreads();

    // --- stage image rows 0..255 -> ly=1..256, cols x -> lx=x+2 (word 2q+1..) ---
    const float4* img4 = (const float4*)(img + batch * (NVOL * NVOL));
    __half2* Lh2 = (__half2*)L;
    #pragma unroll
    for (int it = 0; it < 16; ++it) {
        int g = tid + (it << 10);
        int r = g >> 6, q = g & 63;            // row 0..255, float4 index 0..63
        float4 v = img4[g];
        int w = (r + 1) * RW + (q << 1) + 1;   // halves lx = 4q+2 .. 4q+5
        Lh2[w]     = __floats2half2_rn(v.x, v.y);
        Lh2[w + 1] = __floats2half2_rn(v.z, v.w);
    }
    __syncthreads();

    const int lane = tid & 63;
    unsigned int* ctr = &cnt[(((unsigned)batch << 1) | (unsigned)half) << 5]; // 128B apart
    const unsigned ubase  = half ? (unsigned)(NU / 2) : 0u;
    const unsigned ucount = half ? (unsigned)(NU - NU / 2) : (unsigned)(NU / 2);
    float* outb = out + batch * (NANG * NDET);
    const float Bx = 128.499f;

    for (;;) {
        unsigned u = 0;
        if (lane == 0) u = atomicAdd(ctr, 1u);
        u = (unsigned)__shfl((int)u, 0);
        if (u >= ucount) break;
        u += ubase;
        int a    = (int)(u / (unsigned)NCHUNK);
        int det0 = (int)(u - (unsigned)a * NCHUNK) * RCHUNK;

        float ang = (float)a * 0.017453292519943295f;
        float si = __sinf(ang), c = __cosf(ang);
        float nsi = -si;
        float rsi = __builtin_amdgcn_rcpf(si);   // used only when si > eps
        float rc  = __builtin_amdgcn_rcpf(c);    // used only when |c| > eps

        for (int rr = 0; rr < RCHUNK; ++rr) {
            int det = det0 + rr;
            if (det >= NDET) break;
            float s  = (float)det - 181.0f;
            float sx = s * c, sy = s * si;

            float tlo = -181.0f, thi = 181.0f;
            bool ok = true;
            if (si > 1e-6f) {
                tlo = fmaxf(tlo, (sx - Bx) * rsi);
                thi = fminf(thi, (sx + Bx) * rsi);
            } else if (fabsf(sx) > Bx) ok = false;
            if (c > 1e-6f) {
                tlo = fmaxf(tlo, (-Bx - sy) * rc);
                thi = fminf(thi, ( Bx - sy) * rc);
            } else if (c < -1e-6f) {
                tlo = fmaxf(tlo, ( Bx - sy) * rc);
                thi = fminf(thi, (-Bx - sy) * rc);
            } else if (fabsf(sy) > Bx) ok = false;
            tlo += 1e-3f; thi -= 1e-3f;          // drops only weight<=1e-3 edge taps

            int k0 = max(0,   (int)ceilf(tlo + 181.0f));
            int k1 = min(362, (int)floorf(thi + 181.0f));

            float acc = 0.0f;
            if (ok) {
                float lfx0 = sx + 129.5f;        // +2 col guard offset
                float lfy0 = sy + 128.5f;        // +1 row guard offset
                float tf = (float)(k0 + lane) - 181.0f;
                for (int k = k0 + lane; k <= k1; k += 64, tf += 64.0f) {
                    float fx = fmaf(tf, nsi, lfx0);
                    float fy = fmaf(tf, c,   lfy0);
                    float xf = floorf(fx), yf = floorf(fy);
                    float wx = fx - xf,   wy = fy - yf;
                    int ix = (int)xf, iy = (int)yf;
                    const unsigned* row = &L[iy * RW + (ix >> 1)];
                    unsigned w00 = row[0],  w01 = row[1];
                    unsigned w10 = row[RW], w11 = row[RW + 1];
                    unsigned sh = (unsigned)(ix & 1) << 4;
                    unsigned p0 = __builtin_amdgcn_alignbit(w01, w00, sh);
                    unsigned p1 = __builtin_amdgcn_alignbit(w11, w10, sh);
                    float2 f0 = __half22float2(__builtin_bit_cast(__half2, p0));
                    float2 f1 = __half22float2(__builtin_bit_cast(__half2, p1));
                    float c0 = fmaf(wy, f1.x - f0.x, f0.x);
                    float c1 = fmaf(wy, f1.y - f0.y, f0.y);
                    acc += fmaf(wx, c1 - c0, c0);
                }
            }
            // full-wave reduce; every ray (det<NDET) gets stored, even empty ones
            for (int off = 32; off; off >>= 1) acc += __shfl_xor(acc, off);
            if (lane == 0) outb[a * NDET + det] = acc;
        }
    }
}

extern "C" void kernel_launch(void* const* d_in, const int* in_sizes, int n_in,
                              void* d_out, int out_size, void* d_ws, size_t ws_size,
                              hipStream_t stream) {
    const float* img = (const float*)d_in[0];
    float* out = (float*)d_out;
    unsigned int* cnt = (unsigned int*)d_ws;

    hipFuncSetAttribute((const void*)proj_kernel,
                        hipFuncAttributeMaxDynamicSharedMemorySize, (int)LDS_BYTES);
    hipMemsetAsync(d_ws, 0, 4 * 32 * sizeof(unsigned int), stream);
    proj_kernel<<<256, 1024, LDS_BYTES, stream>>>(img, out, cnt);
}